// Round 1
// baseline (339.169 us; speedup 1.0000x reference)
//
#include <hip/hip_runtime.h>
#include <hip/hip_bf16.h>

// InvertAffine: input trf (B, 3, 4) fp32 "affine shift" matrices.
// M = [[I3 + T3x3, t], [0,0,0,1]]; output = inv(M)[:3,:] = [A^-1, -A^-1 t].
// Closed-form 3x3 adjugate inverse; A = I + 0.1*noise -> det ~ 1, well-conditioned.
// Memory-bound: 402 MB total traffic, roofline ~64 us at 6.3 TB/s.

__global__ __launch_bounds__(256) void InvertAffine_kernel(
    const float4* __restrict__ in, float4* __restrict__ out, int n) {
    int idx = blockIdx.x * blockDim.x + threadIdx.x;
    int stride = gridDim.x * blockDim.x;
    for (int i = idx; i < n; i += stride) {
        // Each matrix = 3 contiguous float4 rows: [a0 a1 a2 | t]
        float4 r0 = in[i * 3 + 0];
        float4 r1 = in[i * 3 + 1];
        float4 r2 = in[i * 3 + 2];

        float a00 = 1.0f + r0.x, a01 = r0.y,        a02 = r0.z,        t0 = r0.w;
        float a10 = r1.x,        a11 = 1.0f + r1.y, a12 = r1.z,        t1 = r1.w;
        float a20 = r2.x,        a21 = r2.y,        a22 = 1.0f + r2.z, t2 = r2.w;

        // Adjugate (cofactor) inverse of A
        float c00 = a11 * a22 - a12 * a21;
        float c01 = a12 * a20 - a10 * a22;
        float c02 = a10 * a21 - a11 * a20;
        float det = a00 * c00 + a01 * c01 + a02 * c02;
        float rdet = 1.0f / det;

        float i00 = c00 * rdet;
        float i01 = (a02 * a21 - a01 * a22) * rdet;
        float i02 = (a01 * a12 - a02 * a11) * rdet;
        float i10 = c01 * rdet;
        float i11 = (a00 * a22 - a02 * a20) * rdet;
        float i12 = (a02 * a10 - a00 * a12) * rdet;
        float i20 = c02 * rdet;
        float i21 = (a01 * a20 - a00 * a21) * rdet;
        float i22 = (a00 * a11 - a01 * a10) * rdet;

        // Translation column: -A^-1 * t
        float o0 = -(i00 * t0 + i01 * t1 + i02 * t2);
        float o1 = -(i10 * t0 + i11 * t1 + i12 * t2);
        float o2 = -(i20 * t0 + i21 * t1 + i22 * t2);

        out[i * 3 + 0] = make_float4(i00, i01, i02, o0);
        out[i * 3 + 1] = make_float4(i10, i11, i12, o1);
        out[i * 3 + 2] = make_float4(i20, i21, i22, o2);
    }
}

extern "C" void kernel_launch(void* const* d_in, const int* in_sizes, int n_in,
                              void* d_out, int out_size, void* d_ws, size_t ws_size,
                              hipStream_t stream) {
    const float4* in = (const float4*)d_in[0];
    float4* out = (float4*)d_out;
    int n = in_sizes[0] / 12;  // number of (3,4) matrices

    const int block = 256;
    int blocks = (n + block - 1) / block;
    // Cap grid and grid-stride (Guideline 11): 256 CUs x 8 blocks/CU = 2048
    if (blocks > 2048) blocks = 2048;
    InvertAffine_kernel<<<blocks, block, 0, stream>>>(in, out, n);
}